// Round 1
// baseline (2568.367 us; speedup 1.0000x reference)
//
#include <hip/hip_runtime.h>

typedef unsigned short u16;
typedef __bf16 bf16x8 __attribute__((ext_vector_type(8)));
typedef float floatx4 __attribute__((ext_vector_type(4)));

#define DEPTH 2
#define DIM 512
#define HEADS 8
#define DH 64
#define SEG 512
#define PMEM 4
#define VOCAB 32000
#define BB 2
#define SLEN 4096
#define ROWS (BB * SLEN)   // 8192
#define HD 512
#define FFI 1365
#define FF2C 2730          // 2*FFI
#define FFIP 1376          // FFI padded to %32
#define KEYS 516           // PMEM + SEG
#define KEYP 544           // padded to %32
#define NSEG 128           // B*W*H segments

__device__ __forceinline__ u16 f2bf(float f) {
  unsigned u = __float_as_uint(f);
  return (u16)((u + 0x7FFFu + ((u >> 16) & 1u)) >> 16);  // RNE
}
__device__ __forceinline__ float bf2f(u16 v) {
  return __uint_as_float(((unsigned)v) << 16);
}

// ---------------- embedding: x[r] = tok_emb[tok[r]] + pos_emb[s] ----------------
__global__ void embed_kernel(const int* __restrict__ tok, const float* __restrict__ te,
                             const float* __restrict__ pe, float* __restrict__ x) {
  int r = blockIdx.x;
  int t = tok[r];
  int s = r & (SLEN - 1);
  int c = threadIdx.x;  // 128 threads, float4 each
  float4 a = ((const float4*)(te + (long)t * DIM))[c];
  float4 b = ((const float4*)(pe + (long)s * DIM))[c];
  float4 o;
  o.x = a.x + b.x; o.y = a.y + b.y; o.z = a.z + b.z; o.w = a.w + b.w;
  ((float4*)(x + (long)r * DIM))[c] = o;
}

// ---------------- rmsnorm f32 -> bf16, one wave per row ----------------
__global__ void rmsnorm_kernel(const float* __restrict__ x, const float* __restrict__ w,
                               u16* __restrict__ out) {
  int r = blockIdx.x, l = threadIdx.x;  // 64 threads
  const float4* xr = (const float4*)(x + (long)r * DIM);
  float4 a = xr[l], b = xr[l + 64];
  float ss = a.x * a.x + a.y * a.y + a.z * a.z + a.w * a.w +
             b.x * b.x + b.y * b.y + b.z * b.z + b.w * b.w;
  for (int o = 32; o; o >>= 1) ss += __shfl_xor(ss, o);
  float rs = rsqrtf(ss * (1.0f / DIM) + 1e-6f);
  const float4* wr = (const float4*)w;
  float4 wa = wr[l], wb = wr[l + 64];
  u16* orow = out + (long)r * DIM;
  uint2 pa, pb;
  pa.x = (unsigned)f2bf(a.x * rs * wa.x) | ((unsigned)f2bf(a.y * rs * wa.y) << 16);
  pa.y = (unsigned)f2bf(a.z * rs * wa.z) | ((unsigned)f2bf(a.w * rs * wa.w) << 16);
  pb.x = (unsigned)f2bf(b.x * rs * wb.x) | ((unsigned)f2bf(b.y * rs * wb.y) << 16);
  pb.y = (unsigned)f2bf(b.z * rs * wb.z) | ((unsigned)f2bf(b.w * rs * wb.w) << 16);
  *(uint2*)&orow[4 * l] = pa;
  *(uint2*)&orow[4 * l + 256] = pb;
}

// ---------------- weight transpose+cast: W f32 [K][N] -> Bt bf16 [N][Kpad] ----------------
__global__ void transpose_w(const float* __restrict__ Wm, u16* __restrict__ Bt,
                            int K, int N, int Kpad) {
  __shared__ float tile[32][33];
  int n0 = blockIdx.x * 32, k0 = blockIdx.y * 32;
  int tx = threadIdx.x, ty = threadIdx.y;  // (32,8)
  for (int yy = 0; yy < 32; yy += 8) {
    int k = k0 + ty + yy, n = n0 + tx;
    tile[ty + yy][tx] = (k < K && n < N) ? Wm[(long)k * N + n] : 0.0f;
  }
  __syncthreads();
  for (int yy = 0; yy < 32; yy += 8) {
    int n = n0 + ty + yy, k = k0 + tx;
    if (n < N && k < Kpad) Bt[(long)n * Kpad + k] = f2bf(tile[tx][ty + yy]);
  }
}

// ---------------- vmix: mix = sigmoid(xn @ vmix_w + vmix_b), one wave/row ----------------
__global__ void vmix_kernel(const u16* __restrict__ xn, const float* __restrict__ wv,
                            const float* __restrict__ bv, float* __restrict__ mix) {
  int r = blockIdx.x, l = threadIdx.x;  // 64 threads
  int h = l & 7, c = l >> 3;
  const u16* xr = xn + (long)r * DIM;
  float acc = 0.f;
  for (int k = c * 64; k < c * 64 + 64; ++k) acc += bf2f(xr[k]) * wv[k * 8 + h];
  acc += __shfl_xor(acc, 8);
  acc += __shfl_xor(acc, 16);
  acc += __shfl_xor(acc, 32);
  if (l < 8) mix[(long)r * 8 + h] = 1.0f / (1.0f + __expf(-(acc + bv[h])));
}

// ---------------- rope + segment pack (Qs/Ks/Vt) + persistent-mem prefix + pads ----------
// z ordering: z = (b*8 + w)*8 + h
__global__ void rope_seg_kernel(const u16* __restrict__ qkv, const u16* __restrict__ qkv0,
                                const float* __restrict__ mix, const float* __restrict__ pmem,
                                u16* __restrict__ Qs, u16* __restrict__ Ks, u16* __restrict__ Vt) {
  int zi = blockIdx.x;
  int z = zi >> 2, part = zi & 3;
  int h = z & 7, w = (z >> 3) & 7, b = z >> 6;
  long qsb = (long)z * SEG * DH, ksb = (long)z * KEYP * DH, vtb = (long)z * DH * KEYP;
  int i0 = part * 128;
  for (int t = threadIdx.x; t < 128 * 32; t += 256) {
    int i = i0 + (t >> 5), pp = t & 31;
    int s = w * SEG + i;
    long row = (long)b * SLEN + s;
    const u16* qr = qkv + row * 1536 + h * 64 + 2 * pp;
    float q1 = bf2f(qr[0]), q2 = bf2f(qr[1]);
    float k1 = bf2f(qr[512]), k2 = bf2f(qr[513]);
    float v1 = bf2f(qr[1024]), v2 = bf2f(qr[1025]);
    float inv = __expf(-(float)pp * 0.28782313662f);  // 10000^(-pp/32)
    float sn, cs;
    sincosf((float)s * inv, &sn, &cs);
    unsigned qo = (unsigned)f2bf(q1 * cs - q2 * sn) | ((unsigned)f2bf(q1 * sn + q2 * cs) << 16);
    *(unsigned*)&Qs[qsb + (long)i * 64 + 2 * pp] = qo;
    unsigned ko = (unsigned)f2bf(k1 * cs - k2 * sn) | ((unsigned)f2bf(k1 * sn + k2 * cs) << 16);
    *(unsigned*)&Ks[ksb + (long)(PMEM + i) * 64 + 2 * pp] = ko;
    if (mix) {  // value-residual lerp toward layer-0 v
      float m = mix[row * 8 + h];
      float vr1 = bf2f(qkv0[row * 1536 + 1024 + h * 64 + 2 * pp]);
      float vr2 = bf2f(qkv0[row * 1536 + 1024 + h * 64 + 2 * pp + 1]);
      v1 += (vr1 - v1) * m;
      v2 += (vr2 - v2) * m;
    }
    Vt[vtb + (long)(2 * pp) * KEYP + PMEM + i] = f2bf(v1);
    Vt[vtb + (long)(2 * pp + 1) * KEYP + PMEM + i] = f2bf(v2);
  }
  if (part == 0) {  // persistent-memory prefix (no rope)
    for (int t = threadIdx.x; t < PMEM * 64; t += 256) {
      int j = t >> 6, dh = t & 63;
      float pk = pmem[(h * PMEM + j) * 64 + dh];
      float pv = pmem[HEADS * PMEM * 64 + (h * PMEM + j) * 64 + dh];
      Ks[ksb + (long)j * 64 + dh] = f2bf(pk);
      Vt[vtb + (long)dh * KEYP + j] = f2bf(pv);
    }
  } else if (part == 1) {  // zero K pad rows
    for (int t = threadIdx.x; t < (KEYP - KEYS) * 64; t += 256) {
      int j = KEYS + (t >> 6), dh = t & 63;
      Ks[ksb + (long)j * 64 + dh] = 0;
    }
  } else if (part == 2) {  // zero V pad cols
    for (int t = threadIdx.x; t < 64 * (KEYP - KEYS); t += 256) {
      int dh = t / (KEYP - KEYS), j = KEYS + t % (KEYP - KEYS);
      Vt[vtb + (long)dh * KEYP + j] = 0;
    }
  }
}

// ---------------- masked softmax over one score row (valid keys = i+PMEM+1) -----------
__global__ void softmax_kernel(u16* __restrict__ SC) {
  long rowid = blockIdx.x;  // z*512 + i
  int i = (int)(rowid & (SEG - 1));
  u16* row = SC + rowid * KEYP;
  int l = threadIdx.x;  // 64
  int nv = i + PMEM + 1;
  float v[9];
  float mx = -1e30f;
#pragma unroll
  for (int t = 0; t < 9; ++t) {
    int j = l + t * 64;
    v[t] = (j < nv) ? bf2f(row[j]) * 0.125f : -1e30f;  // scale = DH^-0.5
    mx = fmaxf(mx, v[t]);
  }
  for (int o = 32; o; o >>= 1) mx = fmaxf(mx, __shfl_xor(mx, o));
  float sum = 0.f;
#pragma unroll
  for (int t = 0; t < 9; ++t) {
    int j = l + t * 64;
    v[t] = (j < nv) ? __expf(v[t] - mx) : 0.0f;
    sum += v[t];
  }
  for (int o = 32; o; o >>= 1) sum += __shfl_xor(sum, o);
  float is = 1.0f / sum;
#pragma unroll
  for (int t = 0; t < 9; ++t) {
    int j = l + t * 64;
    if (j < KEYP) row[j] = f2bf(v[t] * is);
  }
}

// ---------------- GEGLU: gg = silu(g)*a, zero-padded to FFIP ----------------
__global__ void geglu_kernel(const u16* __restrict__ h1, u16* __restrict__ gg) {
  long r = blockIdx.x;
  const u16* hr = h1 + r * FF2C;
  u16* orow = gg + r * FFIP;
  for (int j = threadIdx.x; j < FFIP; j += 256) {
    float val = 0.0f;
    if (j < FFI) {
      float a = bf2f(hr[j]);
      float g = bf2f(hr[FFI + j]);
      val = a * g / (1.0f + __expf(-g));
    }
    orow[j] = f2bf(val);
  }
}

// ---------------- bf16 MFMA GEMM: C = A[M,K] * Bt[N,K]^T (+bias)(+resid) --------------
// 128x128 tile, BK=32, 256 thr = 4 waves in 2x2, 64x64 per wave (4x4 MFMA 16x16x32).
// Batched via grid.z; C offset decomposed as (z&7)*csh + ((z>>3)&7)*csw + (z>>6)*csb.
__global__ __launch_bounds__(256, 2) void gemm_bf16(
    const u16* __restrict__ A, int lda, long strideA,
    const u16* __restrict__ B, int ldb, long strideB,
    void* __restrict__ Cv, int ldc, long csh, long csw, long csb,
    int M, int N, int K,
    const float* __restrict__ bias, const float* __restrict__ resid, int out_bf16) {
  __shared__ u16 As[128 * 40];
  __shared__ u16 Bs[128 * 40];
  const int z = blockIdx.z;
  const long aoff = (long)z * strideA;
  const long boff = (long)z * strideB;
  const long coff = (long)(z & 7) * csh + (long)((z >> 3) & 7) * csw + (long)(z >> 6) * csb;
  const int m0 = blockIdx.x * 128;
  const int n0 = blockIdx.y * 128;
  const int tid = threadIdx.x;
  const int lane = tid & 63;
  const int col = lane & 15;
  const int quad = lane >> 4;
  const int wv = tid >> 6;
  const int wm = (wv >> 1) * 64;
  const int wn = (wv & 1) * 64;

  floatx4 acc[4][4] = {};

  for (int k0 = 0; k0 < K; k0 += 32) {
    __syncthreads();
#pragma unroll
    for (int p = 0; p < 2; ++p) {
      int li = p * 256 + tid;
      int row = li >> 2, ks = (li & 3) << 3;
      uint4 d = *(const uint4*)(A + aoff + (long)(m0 + row) * lda + (k0 + ks));
      *(uint4*)&As[row * 40 + ks] = d;
    }
#pragma unroll
    for (int p = 0; p < 2; ++p) {
      int li = p * 256 + tid;
      int row = li >> 2, ks = (li & 3) << 3;
      int gn = n0 + row;
      uint4 d = make_uint4(0u, 0u, 0u, 0u);
      if (gn < N) d = *(const uint4*)(B + boff + (long)gn * ldb + (k0 + ks));
      *(uint4*)&Bs[row * 40 + ks] = d;
    }
    __syncthreads();
    bf16x8 af[4], bfr[4];
#pragma unroll
    for (int i = 0; i < 4; ++i)
      af[i] = *(const bf16x8*)&As[(wm + i * 16 + col) * 40 + quad * 8];
#pragma unroll
    for (int j = 0; j < 4; ++j)
      bfr[j] = *(const bf16x8*)&Bs[(wn + j * 16 + col) * 40 + quad * 8];
#pragma unroll
    for (int i = 0; i < 4; ++i)
#pragma unroll
      for (int j = 0; j < 4; ++j)
        acc[i][j] = __builtin_amdgcn_mfma_f32_16x16x32_bf16(af[i], bfr[j], acc[i][j], 0, 0, 0);
  }

#pragma unroll
  for (int i = 0; i < 4; ++i) {
#pragma unroll
    for (int j = 0; j < 4; ++j) {
      int n = n0 + wn + j * 16 + col;
      if (n >= N) continue;
      float bv = bias ? bias[n] : 0.0f;
#pragma unroll
      for (int r = 0; r < 4; ++r) {
        int m = m0 + wm + i * 16 + quad * 4 + r;
        if (m >= M) continue;
        long ci = coff + (long)m * ldc + n;
        float v = acc[i][j][r] + bv;
        if (resid) v += resid[ci];
        if (out_bf16) ((u16*)Cv)[ci] = f2bf(v);
        else ((float*)Cv)[ci] = v;
      }
    }
  }
}

static void launch_gemm(hipStream_t stream, const u16* A, int lda, long sA,
                        const u16* B, int ldb, long sB, void* C, int ldc,
                        long csh, long csw, long csb, int M, int N, int K, int Z,
                        const float* bias, const float* resid, int out_bf16) {
  dim3 grid((M + 127) / 128, (N + 127) / 128, Z);
  gemm_bf16<<<grid, 256, 0, stream>>>(A, lda, sA, B, ldb, sB, C, ldc, csh, csw, csb,
                                      M, N, K, bias, resid, out_bf16);
}

extern "C" void kernel_launch(void* const* d_in, const int* in_sizes, int n_in,
                              void* d_out, int out_size, void* d_ws, size_t ws_size,
                              hipStream_t stream) {
  (void)in_sizes; (void)n_in; (void)out_size; (void)ws_size;
  const int* tokens = (const int*)d_in[0];
  const float* tok_emb = (const float*)d_in[1];
  const float* pos_emb = (const float*)d_in[2];
  const float* attn_norm_w = (const float*)d_in[3];
  const float* Wqkv = (const float*)d_in[4];
  const float* persist = (const float*)d_in[5];
  const float* Wout = (const float*)d_in[6];
  const float* vmix_w = (const float*)d_in[7];
  const float* vmix_b = (const float*)d_in[8];
  const float* ff_norm_w = (const float*)d_in[9];
  const float* ff_w1 = (const float*)d_in[10];
  const float* ff_b1 = (const float*)d_in[11];
  const float* ff_w2 = (const float*)d_in[12];
  const float* ff_b2 = (const float*)d_in[13];
  const float* final_norm_w = (const float*)d_in[14];
  const float* w_logits = (const float*)d_in[15];
  float* out = (float*)d_out;

  char* wsb = (char*)d_ws;
  size_t off = 0;
  auto alloc = [&](size_t n) {
    off = (off + 255) & ~(size_t)255;
    void* r = wsb + off;
    off += n;
    return r;
  };
  float* x   = (float*)alloc((size_t)ROWS * DIM * 4);
  u16* xn    = (u16*)alloc((size_t)ROWS * DIM * 2);
  u16* qkv0  = (u16*)alloc((size_t)ROWS * 1536 * 2);
  u16* qkv1  = (u16*)alloc((size_t)ROWS * 1536 * 2);
  float* mix = (float*)alloc((size_t)ROWS * 8 * 4);
  u16* Qs    = (u16*)alloc((size_t)NSEG * SEG * DH * 2);
  u16* Ks    = (u16*)alloc((size_t)NSEG * KEYP * DH * 2);
  u16* Vt    = (u16*)alloc((size_t)NSEG * DH * KEYP * 2);
  u16* SC    = (u16*)alloc((size_t)NSEG * SEG * KEYP * 2);
  u16* ao    = (u16*)alloc((size_t)ROWS * HD * 2);
  u16* h1    = (u16*)alloc((size_t)ROWS * FF2C * 2);
  u16* gg    = (u16*)alloc((size_t)ROWS * FFIP * 2);
  u16* WqkvT = (u16*)alloc((size_t)2 * 1536 * 512 * 2);
  u16* WoutT = (u16*)alloc((size_t)2 * 512 * 512 * 2);
  u16* Wff1T = (u16*)alloc((size_t)2 * FF2C * 512 * 2);
  u16* Wff2T = (u16*)alloc((size_t)2 * 512 * FFIP * 2);
  u16* WlogT = (u16*)alloc((size_t)VOCAB * 512 * 2);

  dim3 tb(32, 8);
  // weight transposes (f32 [K][N] -> bf16 [N][Kpad])
  transpose_w<<<dim3(48, 16), tb, 0, stream>>>(Wqkv, WqkvT, 512, 1536, 512);
  transpose_w<<<dim3(48, 16), tb, 0, stream>>>(Wqkv + 512 * 1536, WqkvT + 1536 * 512, 512, 1536, 512);
  transpose_w<<<dim3(16, 16), tb, 0, stream>>>(Wout, WoutT, 512, 512, 512);
  transpose_w<<<dim3(16, 16), tb, 0, stream>>>(Wout + 512 * 512, WoutT + 512 * 512, 512, 512, 512);
  transpose_w<<<dim3(86, 16), tb, 0, stream>>>(ff_w1, Wff1T, 512, FF2C, 512);
  transpose_w<<<dim3(86, 16), tb, 0, stream>>>(ff_w1 + 512 * FF2C, Wff1T + FF2C * 512, 512, FF2C, 512);
  transpose_w<<<dim3(16, 43), tb, 0, stream>>>(ff_w2, Wff2T, FFI, 512, FFIP);
  transpose_w<<<dim3(16, 43), tb, 0, stream>>>(ff_w2 + FFI * 512, Wff2T + 512 * FFIP, FFI, 512, FFIP);
  transpose_w<<<dim3(1000, 16), tb, 0, stream>>>(w_logits, WlogT, 512, VOCAB, 512);

  embed_kernel<<<ROWS, 128, 0, stream>>>(tokens, tok_emb, pos_emb, x);

  for (int d = 0; d < DEPTH; ++d) {
    u16* qkvd = d ? qkv1 : qkv0;
    rmsnorm_kernel<<<ROWS, 64, 0, stream>>>(x, attn_norm_w + d * DIM, xn);
    launch_gemm(stream, xn, 512, 0, WqkvT + (size_t)d * 1536 * 512, 512, 0, qkvd, 1536,
                0, 0, 0, ROWS, 1536, 512, 1, nullptr, nullptr, 1);
    if (d) vmix_kernel<<<ROWS, 64, 0, stream>>>(xn, vmix_w + d * DIM * HEADS, vmix_b + d * HEADS, mix);
    rope_seg_kernel<<<NSEG * 4, 256, 0, stream>>>(qkvd, qkv0, d ? mix : nullptr,
                                                  persist + (size_t)d * 2 * HEADS * PMEM * DH,
                                                  Qs, Ks, Vt);
    // scores = Qs @ Ks^T  (batched over 128 segments)
    launch_gemm(stream, Qs, 64, (long)SEG * 64, Ks, 64, (long)KEYP * 64, SC, KEYP,
                (long)SEG * KEYP, 8L * SEG * KEYP, 64L * SEG * KEYP,
                SEG, KEYP, 64, NSEG, nullptr, nullptr, 1);
    softmax_kernel<<<NSEG * SEG, 64, 0, stream>>>(SC);
    // o = P @ V  -> scatter into [B,S,HD] layout via csh/csw/csb
    launch_gemm(stream, SC, KEYP, (long)SEG * KEYP, Vt, KEYP, (long)DH * KEYP, ao, HD,
                64L, 512L * 512, 4096L * 512, SEG, DH, KEYP, NSEG, nullptr, nullptr, 1);
    // x += o @ Wout
    launch_gemm(stream, ao, 512, 0, WoutT + (size_t)d * 512 * 512, 512, 0, x, 512,
                0, 0, 0, ROWS, 512, 512, 1, nullptr, x, 0);
    // FF
    rmsnorm_kernel<<<ROWS, 64, 0, stream>>>(x, ff_norm_w + d * DIM, xn);
    launch_gemm(stream, xn, 512, 0, Wff1T + (size_t)d * FF2C * 512, 512, 0, h1, FF2C,
                0, 0, 0, ROWS, FF2C, 512, 1, ff_b1 + d * FF2C, nullptr, 1);
    geglu_kernel<<<ROWS, 256, 0, stream>>>(h1, gg);
    launch_gemm(stream, gg, FFIP, 0, Wff2T + (size_t)d * 512 * FFIP, FFIP, 0, x, 512,
                0, 0, 0, ROWS, 512, FFIP, 1, ff_b2 + d * DIM, x, 0);
  }
  rmsnorm_kernel<<<ROWS, 64, 0, stream>>>(x, final_norm_w, xn);
  launch_gemm(stream, xn, 512, 0, WlogT, 512, 0, out, VOCAB,
              0, 0, 0, ROWS, VOCAB, 512, 1, nullptr, nullptr, 0);
}